// Round 1
// baseline (1754.475 us; speedup 1.0000x reference)
//
#include <hip/hip_runtime.h>
#include <math.h>

#define NB 16
#define L 1024
#define D 256
#define INV_EPS 10.0f
#define N_ITER 50
#define LOG_MU (-6.9314718055994531f)   // -log(1024), same for log_nu

// ---------------- norms: x2[row] = sum_k x[row,k]^2 -----------------
__global__ __launch_bounds__(256) void norms_kernel(
    const float* __restrict__ x, const float* __restrict__ y,
    float* __restrict__ x2, float* __restrict__ y2) {
  int wid = threadIdx.x >> 6, lane = threadIdx.x & 63;
  int row = blockIdx.x * 4 + wid;                   // 0 .. 2*NB*L-1
  const float* src = (row < NB * L) ? (x + (size_t)row * D)
                                    : (y + (size_t)(row - NB * L) * D);
  float4 v = *(const float4*)(src + lane * 4);
  float s = v.x * v.x + v.y * v.y + v.z * v.z + v.w * v.w;
  #pragma unroll
  for (int off = 32; off; off >>= 1) s += __shfl_down(s, off);
  if (lane == 0) {
    if (row < NB * L) x2[row] = s;
    else              y2[row - NB * L] = s;
  }
}

// ---------------- cost: C[b,i,j] = ||x_i - y_j||, optional transpose ----
template <int WRITE_T>
__global__ __launch_bounds__(256) void cost_kernel(
    const float* __restrict__ x, const float* __restrict__ y,
    const float* __restrict__ x2, const float* __restrict__ y2,
    float* __restrict__ C, float* __restrict__ CT) {
  __shared__ float xs[16][68];   // [k][row], pad 64->68 keeps b128 16B-aligned,
  __shared__ float ys[16][68];   // conflict-free reads, 2-way (free) writes
  int bid = blockIdx.x;
  int b = bid >> 8;
  int rem = bid & 255;
  int i0 = (rem >> 4) << 6;
  int j0 = (rem & 15) << 6;
  int tid = threadIdx.x;
  int tx = tid & 15, ty = tid >> 4;
  int r = tid >> 2, kq = tid & 3;

  float acc[4][4] = {};
  const float* xbase = x + ((size_t)b * L + i0 + r) * D + kq * 4;
  const float* ybase = y + ((size_t)b * L + j0 + r) * D + kq * 4;

  for (int k0 = 0; k0 < D; k0 += 16) {
    float4 xv = *(const float4*)(xbase + k0);
    float4 yv = *(const float4*)(ybase + k0);
    __syncthreads();
    xs[kq * 4 + 0][r] = xv.x; xs[kq * 4 + 1][r] = xv.y;
    xs[kq * 4 + 2][r] = xv.z; xs[kq * 4 + 3][r] = xv.w;
    ys[kq * 4 + 0][r] = yv.x; ys[kq * 4 + 1][r] = yv.y;
    ys[kq * 4 + 2][r] = yv.z; ys[kq * 4 + 3][r] = yv.w;
    __syncthreads();
    #pragma unroll
    for (int kk = 0; kk < 16; ++kk) {
      float4 av = *(const float4*)&xs[kk][ty * 4];
      float4 bv = *(const float4*)&ys[kk][tx * 4];
      float a[4] = {av.x, av.y, av.z, av.w};
      float bb[4] = {bv.x, bv.y, bv.z, bv.w};
      #pragma unroll
      for (int er = 0; er < 4; ++er)
        #pragma unroll
        for (int ec = 0; ec < 4; ++ec)
          acc[er][ec] = fmaf(a[er], bb[ec], acc[er][ec]);
    }
  }

  float xr[4], yc[4];
  #pragma unroll
  for (int e = 0; e < 4; ++e) {
    xr[e] = x2[b * L + i0 + ty * 4 + e];
    yc[e] = y2[b * L + j0 + tx * 4 + e];
  }
  float cst[4][4];
  #pragma unroll
  for (int er = 0; er < 4; ++er)
    #pragma unroll
    for (int ec = 0; ec < 4; ++ec) {
      float d2 = xr[er] + yc[ec] - 2.0f * acc[er][ec];
      cst[er][ec] = sqrtf(fmaxf(d2, 0.0f));
    }
  #pragma unroll
  for (int er = 0; er < 4; ++er) {
    float4 cv = {cst[er][0], cst[er][1], cst[er][2], cst[er][3]};
    *(float4*)(C + ((size_t)b * L + i0 + ty * 4 + er) * L + j0 + tx * 4) = cv;
  }
  if (WRITE_T) {
    #pragma unroll
    for (int ec = 0; ec < 4; ++ec) {
      float4 tv = {cst[0][ec], cst[1][ec], cst[2][ec], cst[3][ec]};
      *(float4*)(CT + ((size_t)b * L + j0 + tx * 4 + ec) * L + i0 + ty * 4) = tv;
    }
  }
}

// ------------- row-LSE potential update: out[r] = LOG_MU - LSE_c(g[c] - K[r,c]/eps)
__global__ __launch_bounds__(256) void lse_update_kernel(
    const float* __restrict__ K, const float* __restrict__ gin,
    float* __restrict__ gout) {
  __shared__ float red1[4], red2[4];
  int bid = blockIdx.x;                 // = b*L + row
  int b = bid >> 10;
  const float* row = K + (size_t)bid * L;
  const float* g = gin + b * L;
  int tid = threadIdx.x;
  float4 c4 = *(const float4*)(row + tid * 4);
  float4 g4 = *(const float4*)(g + tid * 4);
  float s0 = g4.x - c4.x * INV_EPS;
  float s1 = g4.y - c4.y * INV_EPS;
  float s2 = g4.z - c4.z * INV_EPS;
  float s3 = g4.w - c4.w * INV_EPS;
  float m = fmaxf(fmaxf(s0, s1), fmaxf(s2, s3));
  #pragma unroll
  for (int off = 32; off; off >>= 1) m = fmaxf(m, __shfl_down(m, off));
  int wid = tid >> 6, lane = tid & 63;
  if (lane == 0) red1[wid] = m;
  __syncthreads();
  m = fmaxf(fmaxf(red1[0], red1[1]), fmaxf(red1[2], red1[3]));
  float p = __expf(s0 - m) + __expf(s1 - m) + __expf(s2 - m) + __expf(s3 - m);
  #pragma unroll
  for (int off = 32; off; off >>= 1) p += __shfl_down(p, off);
  if (lane == 0) red2[wid] = p;
  __syncthreads();
  if (tid == 0) {
    float tot = red2[0] + red2[1] + red2[2] + red2[3];
    gout[bid] = LOG_MU - (m + __logf(tot));
  }
}

// ------------- fallback column update (no transposed copy) ---------------
__global__ __launch_bounds__(256) void col_update_kernel(
    const float* __restrict__ C, const float* __restrict__ log_u,
    float* __restrict__ log_v) {
  __shared__ float ms[4][64], ss[4][64];
  int bid = blockIdx.x;                 // NB * (L/64) = 256 blocks
  int b = bid >> 4;
  int j0 = (bid & 15) << 6;
  int tid = threadIdx.x;
  int jj = tid & 63, q = tid >> 6;
  int j = j0 + jj;
  const float* u = log_u + b * L;
  const float* Cb = C + (size_t)b * L * L;
  float m = -INFINITY, s = 0.0f;
  for (int i = q * 256; i < q * 256 + 256; ++i) {
    float sv = u[i] - Cb[(size_t)i * L + j] * INV_EPS;
    float mn = fmaxf(m, sv);
    s = s * __expf(m - mn) + __expf(sv - mn);
    m = mn;
  }
  ms[q][jj] = m; ss[q][jj] = s;
  __syncthreads();
  if (q == 0) {
    float M = fmaxf(fmaxf(ms[0][jj], ms[1][jj]), fmaxf(ms[2][jj], ms[3][jj]));
    float S = ss[0][jj] * __expf(ms[0][jj] - M) + ss[1][jj] * __expf(ms[1][jj] - M) +
              ss[2][jj] * __expf(ms[2][jj] - M) + ss[3][jj] * __expf(ms[3][jj] - M);
    log_v[b * L + j] = LOG_MU - (M + __logf(S));
  }
}

// ------------- final: out += mean_b sum_ij exp(u_i + v_j - C/eps) * C ------
__global__ __launch_bounds__(256) void distance_kernel(
    const float* __restrict__ C, const float* __restrict__ log_u,
    const float* __restrict__ log_v, float* __restrict__ out) {
  __shared__ float red[4];
  int bid = blockIdx.x;                 // = b*L + row
  int b = bid >> 10;
  const float* row = C + (size_t)bid * L;
  const float* v = log_v + b * L;
  float ui = log_u[bid];
  int tid = threadIdx.x;
  float4 c4 = *(const float4*)(row + tid * 4);
  float4 v4 = *(const float4*)(v + tid * 4);
  float s = __expf(ui + v4.x - c4.x * INV_EPS) * c4.x +
            __expf(ui + v4.y - c4.y * INV_EPS) * c4.y +
            __expf(ui + v4.z - c4.z * INV_EPS) * c4.z +
            __expf(ui + v4.w - c4.w * INV_EPS) * c4.w;
  #pragma unroll
  for (int off = 32; off; off >>= 1) s += __shfl_down(s, off);
  int wid = tid >> 6, lane = tid & 63;
  if (lane == 0) red[wid] = s;
  __syncthreads();
  if (tid == 0) {
    float tot = red[0] + red[1] + red[2] + red[3];
    atomicAdd(out, tot * (1.0f / NB));
  }
}

extern "C" void kernel_launch(void* const* d_in, const int* in_sizes, int n_in,
                              void* d_out, int out_size, void* d_ws, size_t ws_size,
                              hipStream_t stream) {
  const float* x = (const float*)d_in[0];
  const float* y = (const float*)d_in[1];
  float* out = (float*)d_out;
  char* ws = (char*)d_ws;

  const size_t szC = (size_t)NB * L * L * sizeof(float);   // 64 MB
  float* C  = (float*)ws;
  float* x2 = (float*)(ws + szC);
  float* y2 = x2 + NB * L;
  float* lu = y2 + NB * L;
  float* lv = lu + NB * L;
  float* CT = (float*)(ws + szC + ((size_t)4 * NB * L * sizeof(float) + 255 & ~(size_t)255));
  const int useT = (ws_size >= 2 * szC + (1u << 20)) ? 1 : 0;

  // init potentials to 0, output accumulator to 0
  hipMemsetAsync(lu, 0, 2 * NB * L * sizeof(float), stream);
  hipMemsetAsync(d_out, 0, sizeof(float), stream);

  norms_kernel<<<2 * NB * L / 4, 256, 0, stream>>>(x, y, x2, y2);
  if (useT)
    cost_kernel<1><<<NB * 256, 256, 0, stream>>>(x, y, x2, y2, C, CT);
  else
    cost_kernel<0><<<NB * 256, 256, 0, stream>>>(x, y, x2, y2, C, C);

  for (int t = 0; t < N_ITER; ++t) {
    lse_update_kernel<<<NB * L, 256, 0, stream>>>(C, lv, lu);       // u-update
    if (useT)
      lse_update_kernel<<<NB * L, 256, 0, stream>>>(CT, lu, lv);    // v-update
    else
      col_update_kernel<<<256, 256, 0, stream>>>(C, lu, lv);
  }
  distance_kernel<<<NB * L, 256, 0, stream>>>(C, lu, lv, out);
}

// Round 2
// 1116.961 us; speedup vs baseline: 1.5708x; 1.5708x over previous
//
#include <hip/hip_runtime.h>
#include <math.h>

#define NB 16
#define L 1024
#define D 256
#define N_ITER 50
#define LOG_MU (-6.9314718055994531f)   // -log(1024), same for log_nu
#define QS (1.0f/256.0f)                // q -> nat-log units
#define QSC (1.0f/2560.0f)              // q -> distance units

typedef short short4_t __attribute__((ext_vector_type(4)));

// ---------------- norms: x2[row] = sum_k x[row,k]^2 -----------------
__global__ __launch_bounds__(256) void norms_kernel(
    const float* __restrict__ x, const float* __restrict__ y,
    float* __restrict__ x2, float* __restrict__ y2) {
  int wid = threadIdx.x >> 6, lane = threadIdx.x & 63;
  int row = blockIdx.x * 4 + wid;                   // 0 .. 2*NB*L-1
  const float* src = (row < NB * L) ? (x + (size_t)row * D)
                                    : (y + (size_t)(row - NB * L) * D);
  float4 v = *(const float4*)(src + lane * 4);
  float s = v.x * v.x + v.y * v.y + v.z * v.z + v.w * v.w;
  #pragma unroll
  for (int off = 32; off; off >>= 1) s += __shfl_down(s, off);
  if (lane == 0) {
    if (row < NB * L) x2[row] = s;
    else              y2[row - NB * L] = s;
  }
}

// ---------------- GEMM pass 1: per-row / per-col min of C ----------------
__global__ __launch_bounds__(256) void costmin_kernel(
    const float* __restrict__ x, const float* __restrict__ y,
    const float* __restrict__ x2, const float* __restrict__ y2,
    int* __restrict__ minrow, int* __restrict__ mincol) {
  __shared__ float xs[16][68];
  __shared__ float ys[16][68];
  __shared__ int rmin[64], cmin[64];
  int bid = blockIdx.x;
  int b = bid >> 8;
  int rem = bid & 255;
  int i0 = (rem >> 4) << 6;
  int j0 = (rem & 15) << 6;
  int tid = threadIdx.x;
  int tx = tid & 15, ty = tid >> 4;
  int r = tid >> 2, kq = tid & 3;
  if (tid < 64) { rmin[tid] = 0x7f7f7f7f; cmin[tid] = 0x7f7f7f7f; }

  float acc[4][4] = {};
  const float* xbase = x + ((size_t)b * L + i0 + r) * D + kq * 4;
  const float* ybase = y + ((size_t)b * L + j0 + r) * D + kq * 4;
  for (int k0 = 0; k0 < D; k0 += 16) {
    float4 xv = *(const float4*)(xbase + k0);
    float4 yv = *(const float4*)(ybase + k0);
    __syncthreads();
    xs[kq * 4 + 0][r] = xv.x; xs[kq * 4 + 1][r] = xv.y;
    xs[kq * 4 + 2][r] = xv.z; xs[kq * 4 + 3][r] = xv.w;
    ys[kq * 4 + 0][r] = yv.x; ys[kq * 4 + 1][r] = yv.y;
    ys[kq * 4 + 2][r] = yv.z; ys[kq * 4 + 3][r] = yv.w;
    __syncthreads();
    #pragma unroll
    for (int kk = 0; kk < 16; ++kk) {
      float4 av = *(const float4*)&xs[kk][ty * 4];
      float4 bv = *(const float4*)&ys[kk][tx * 4];
      float a[4] = {av.x, av.y, av.z, av.w};
      float bb[4] = {bv.x, bv.y, bv.z, bv.w};
      #pragma unroll
      for (int er = 0; er < 4; ++er)
        #pragma unroll
        for (int ec = 0; ec < 4; ++ec)
          acc[er][ec] = fmaf(a[er], bb[ec], acc[er][ec]);
    }
  }
  float xr[4], yc[4];
  #pragma unroll
  for (int e = 0; e < 4; ++e) {
    xr[e] = x2[b * L + i0 + ty * 4 + e];
    yc[e] = y2[b * L + j0 + tx * 4 + e];
  }
  float rm[4] = {3.4e38f, 3.4e38f, 3.4e38f, 3.4e38f};
  float cm[4] = {3.4e38f, 3.4e38f, 3.4e38f, 3.4e38f};
  #pragma unroll
  for (int er = 0; er < 4; ++er)
    #pragma unroll
    for (int ec = 0; ec < 4; ++ec) {
      float d2 = xr[er] + yc[ec] - 2.0f * acc[er][ec];
      float c = sqrtf(fmaxf(d2, 0.0f));
      rm[er] = fminf(rm[er], c);
      cm[ec] = fminf(cm[ec], c);
    }
  #pragma unroll
  for (int e = 0; e < 4; ++e) {
    atomicMin(&rmin[ty * 4 + e], __float_as_int(rm[e]));   // C >= 0: int cmp == float cmp
    atomicMin(&cmin[tx * 4 + e], __float_as_int(cm[e]));
  }
  __syncthreads();
  if (tid < 64)       atomicMin(&minrow[b * L + i0 + tid], rmin[tid]);
  else if (tid < 128) atomicMin(&mincol[b * L + j0 + tid - 64], cmin[tid - 64]);
}

// ---------------- GEMM pass 2: quantize Q[i][j], QT[j][i] ----------------
__global__ __launch_bounds__(256) void wconv_kernel(
    const float* __restrict__ x, const float* __restrict__ y,
    const float* __restrict__ x2, const float* __restrict__ y2,
    const float* __restrict__ minrow, const float* __restrict__ mincol,
    short* __restrict__ Q, short* __restrict__ QT) {
  __shared__ float xs[16][68];
  __shared__ float ys[16][68];
  __shared__ float tile[64][68];
  int bid = blockIdx.x;
  int b = bid >> 8;
  int rem = bid & 255;
  int i0 = (rem >> 4) << 6;
  int j0 = (rem & 15) << 6;
  int tid = threadIdx.x;
  int tx = tid & 15, ty = tid >> 4;
  int r = tid >> 2, kq = tid & 3;

  float acc[4][4] = {};
  const float* xbase = x + ((size_t)b * L + i0 + r) * D + kq * 4;
  const float* ybase = y + ((size_t)b * L + j0 + r) * D + kq * 4;
  for (int k0 = 0; k0 < D; k0 += 16) {
    float4 xv = *(const float4*)(xbase + k0);
    float4 yv = *(const float4*)(ybase + k0);
    __syncthreads();
    xs[kq * 4 + 0][r] = xv.x; xs[kq * 4 + 1][r] = xv.y;
    xs[kq * 4 + 2][r] = xv.z; xs[kq * 4 + 3][r] = xv.w;
    ys[kq * 4 + 0][r] = yv.x; ys[kq * 4 + 1][r] = yv.y;
    ys[kq * 4 + 2][r] = yv.z; ys[kq * 4 + 3][r] = yv.w;
    __syncthreads();
    #pragma unroll
    for (int kk = 0; kk < 16; ++kk) {
      float4 av = *(const float4*)&xs[kk][ty * 4];
      float4 bv = *(const float4*)&ys[kk][tx * 4];
      float a[4] = {av.x, av.y, av.z, av.w};
      float bb[4] = {bv.x, bv.y, bv.z, bv.w};
      #pragma unroll
      for (int er = 0; er < 4; ++er)
        #pragma unroll
        for (int ec = 0; ec < 4; ++ec)
          acc[er][ec] = fmaf(a[er], bb[ec], acc[er][ec]);
    }
  }
  float xr[4], yc[4], mr[4], mc[4];
  #pragma unroll
  for (int e = 0; e < 4; ++e) {
    xr[e] = x2[b * L + i0 + ty * 4 + e];
    yc[e] = y2[b * L + j0 + tx * 4 + e];
    mr[e] = minrow[b * L + i0 + ty * 4 + e];
    mc[e] = mincol[b * L + j0 + ty * 4 + e];  // used in phase 2 (rows ty*4+e of QT)
  }
  float cst[4][4];
  #pragma unroll
  for (int er = 0; er < 4; ++er)
    #pragma unroll
    for (int ec = 0; ec < 4; ++ec) {
      float d2 = xr[er] + yc[ec] - 2.0f * acc[er][ec];
      cst[er][ec] = sqrtf(fmaxf(d2, 0.0f));
    }
  // phase 1: write Q rows (row-shifted quantization), stage cst in LDS
  __syncthreads();
  #pragma unroll
  for (int er = 0; er < 4; ++er) {
    short4_t q4;
    #pragma unroll
    for (int ec = 0; ec < 4; ++ec) {
      int qi = __float2int_rn((mr[er] - cst[er][ec]) * 2560.0f);
      q4[ec] = (short)max(qi, -32767);
      tile[ty * 4 + er][tx * 4 + ec] = cst[er][ec];
    }
    *(short4_t*)(Q + ((size_t)b * L + i0 + ty * 4 + er) * L + j0 + tx * 4) = q4;
  }
  __syncthreads();
  // phase 2: QT rows j_loc = ty*4+eq, cols i_loc = tx*4..+3 (col-shifted)
  #pragma unroll
  for (int eq = 0; eq < 4; ++eq) {
    short4_t q4;
    #pragma unroll
    for (int k = 0; k < 4; ++k) {
      float c = tile[tx * 4 + k][ty * 4 + eq];
      int qi = __float2int_rn((mc[eq] - c) * 2560.0f);
      q4[k] = (short)max(qi, -32767);
    }
    *(short4_t*)(QT + ((size_t)b * L + j0 + ty * 4 + eq) * L + i0 + tx * 4) = q4;
  }
}

// ---------------- Sinkhorn pass: gout[i] = LOG_MU + 10*minC[i] - gmax - log(sum_j exp(q/256 + g_j - gmax))
__global__ __launch_bounds__(256) void pass_kernel(
    const short* __restrict__ Q, const float* __restrict__ shiftC,
    const float* __restrict__ gin, float* __restrict__ gout) {
  int bb = blockIdx.x;                  // 2048 blocks, 8 rows each (same batch)
  int w = threadIdx.x >> 6, lane = threadIdx.x & 63;
  int b = bb >> 7;
  const float4* g4 = (const float4*)(gin + (b << 10));
  float vv[16];
  float4 a0 = g4[lane * 2];             // j = lane*8 .. +3
  float4 a1 = g4[lane * 2 + 1];
  float4 a2 = g4[128 + lane * 2];       // j = 512 + lane*8 ..
  float4 a3 = g4[128 + lane * 2 + 1];
  vv[0]=a0.x; vv[1]=a0.y; vv[2]=a0.z; vv[3]=a0.w;
  vv[4]=a1.x; vv[5]=a1.y; vv[6]=a1.z; vv[7]=a1.w;
  vv[8]=a2.x; vv[9]=a2.y; vv[10]=a2.z; vv[11]=a2.w;
  vv[12]=a3.x; vv[13]=a3.y; vv[14]=a3.z; vv[15]=a3.w;
  float m = vv[0];
  #pragma unroll
  for (int t = 1; t < 16; ++t) m = fmaxf(m, vv[t]);
  #pragma unroll
  for (int off = 32; off; off >>= 1) m = fmaxf(m, __shfl_xor(m, off));
  #pragma unroll
  for (int t = 0; t < 16; ++t) vv[t] -= m;            // w2 in place

  int r0 = bb * 8 + w;
  int r1 = r0 + 4;
  const int4* q0 = (const int4*)(Q + (size_t)r0 * L);
  const int4* q1 = (const int4*)(Q + (size_t)r1 * L);
  int4 c00 = q0[lane], c01 = q0[64 + lane];
  int4 c10 = q1[lane], c11 = q1[64 + lane];
  float acc0 = 0.0f, acc1 = 0.0f;
  #define ACC(A, V, B)                                                     \
    A += __expf(fmaf((float)(short)(V), QS, vv[B]));                       \
    A += __expf(fmaf((float)((V) >> 16), QS, vv[(B) + 1]));
  ACC(acc0, c00.x, 0) ACC(acc0, c00.y, 2) ACC(acc0, c00.z, 4) ACC(acc0, c00.w, 6)
  ACC(acc0, c01.x, 8) ACC(acc0, c01.y, 10) ACC(acc0, c01.z, 12) ACC(acc0, c01.w, 14)
  ACC(acc1, c10.x, 0) ACC(acc1, c10.y, 2) ACC(acc1, c10.z, 4) ACC(acc1, c10.w, 6)
  ACC(acc1, c11.x, 8) ACC(acc1, c11.y, 10) ACC(acc1, c11.z, 12) ACC(acc1, c11.w, 14)
  #undef ACC
  #pragma unroll
  for (int off = 32; off; off >>= 1) {
    acc0 += __shfl_xor(acc0, off);
    acc1 += __shfl_xor(acc1, off);
  }
  if (lane == 0) {
    gout[r0] = LOG_MU + 10.0f * shiftC[r0] - m - __logf(acc0);
    gout[r1] = LOG_MU + 10.0f * shiftC[r1] - m - __logf(acc1);
  }
}

// ---------------- distance partials: sum_j exp(u+v-10C) * C per block -----
__global__ __launch_bounds__(256) void distance_kernel(
    const short* __restrict__ Q, const float* __restrict__ minrow,
    const float* __restrict__ lu, const float* __restrict__ lv,
    float* __restrict__ partial) {
  __shared__ float bp[4];
  int bb = blockIdx.x;
  int w = threadIdx.x >> 6, lane = threadIdx.x & 63;
  int b = bb >> 7;
  const float4* g4 = (const float4*)(lv + (b << 10));
  float vv[16];
  float4 a0 = g4[lane * 2];
  float4 a1 = g4[lane * 2 + 1];
  float4 a2 = g4[128 + lane * 2];
  float4 a3 = g4[128 + lane * 2 + 1];
  vv[0]=a0.x; vv[1]=a0.y; vv[2]=a0.z; vv[3]=a0.w;
  vv[4]=a1.x; vv[5]=a1.y; vv[6]=a1.z; vv[7]=a1.w;
  vv[8]=a2.x; vv[9]=a2.y; vv[10]=a2.z; vv[11]=a2.w;
  vv[12]=a3.x; vv[13]=a3.y; vv[14]=a3.z; vv[15]=a3.w;

  float rs = 0.0f;
  #pragma unroll
  for (int rr = 0; rr < 2; ++rr) {
    int row = bb * 8 + w + rr * 4;
    float mrow = minrow[row];
    float a = lu[row] - 10.0f * mrow;        // T = exp(q/256 + a + v_j)
    const int4* q0 = (const int4*)(Q + (size_t)row * L);
    int4 cA = q0[lane], cB = q0[64 + lane];
    float acc = 0.0f;
    #define ACC2(V, B)                                                      \
      { float qf = (float)(short)(V);                                       \
        float t = __expf(fmaf(qf, QS, a + vv[B]));                          \
        acc = fmaf(t, fmaf(qf, -QSC, mrow), acc);                           \
        qf = (float)((V) >> 16);                                            \
        t = __expf(fmaf(qf, QS, a + vv[(B) + 1]));                          \
        acc = fmaf(t, fmaf(qf, -QSC, mrow), acc); }
    ACC2(cA.x, 0) ACC2(cA.y, 2) ACC2(cA.z, 4) ACC2(cA.w, 6)
    ACC2(cB.x, 8) ACC2(cB.y, 10) ACC2(cB.z, 12) ACC2(cB.w, 14)
    #undef ACC2
    rs += acc;
  }
  #pragma unroll
  for (int off = 32; off; off >>= 1) rs += __shfl_xor(rs, off);
  if (lane == 0) bp[w] = rs;
  __syncthreads();
  if (threadIdx.x == 0) partial[bb] = bp[0] + bp[1] + bp[2] + bp[3];
}

__global__ __launch_bounds__(256) void reduce_kernel(
    const float* __restrict__ partial, float* __restrict__ out) {
  __shared__ float bp[4];
  int tid = threadIdx.x;
  float s = 0.0f;
  #pragma unroll
  for (int k = 0; k < 8; ++k) s += partial[tid + k * 256];
  #pragma unroll
  for (int off = 32; off; off >>= 1) s += __shfl_xor(s, off);
  int w = tid >> 6;
  if ((tid & 63) == 0) bp[w] = s;
  __syncthreads();
  if (tid == 0) out[0] = (bp[0] + bp[1] + bp[2] + bp[3]) * (1.0f / NB);
}

extern "C" void kernel_launch(void* const* d_in, const int* in_sizes, int n_in,
                              void* d_out, int out_size, void* d_ws, size_t ws_size,
                              hipStream_t stream) {
  const float* x = (const float*)d_in[0];
  const float* y = (const float*)d_in[1];
  float* out = (float*)d_out;
  char* ws = (char*)d_ws;

  const size_t szQ = (size_t)NB * L * L * sizeof(short);   // 32 MB
  short* Q  = (short*)ws;
  short* QT = (short*)(ws + szQ);
  int*   minrow = (int*)(ws + 2 * szQ);                    // float bits
  int*   mincol = minrow + NB * L;
  float* x2 = (float*)(mincol + NB * L);
  float* y2 = x2 + NB * L;
  float* lu = y2 + NB * L;
  float* lv = lu + NB * L;
  float* partial = x2;                                     // x2 dead after wconv

  const float* minrowF = (const float*)minrow;
  const float* mincolF = (const float*)mincol;

  hipMemsetAsync(minrow, 0x7f, 2 * NB * L * sizeof(int), stream);  // ~FLT_MAX
  hipMemsetAsync(lv, 0, NB * L * sizeof(float), stream);

  norms_kernel<<<2 * NB * L / 4, 256, 0, stream>>>(x, y, x2, y2);
  costmin_kernel<<<NB * 256, 256, 0, stream>>>(x, y, x2, y2, minrow, mincol);
  wconv_kernel<<<NB * 256, 256, 0, stream>>>(x, y, x2, y2, minrowF, mincolF, Q, QT);

  for (int t = 0; t < N_ITER; ++t) {
    pass_kernel<<<NB * L / 8, 256, 0, stream>>>(Q,  minrowF, lv, lu);   // u-update
    pass_kernel<<<NB * L / 8, 256, 0, stream>>>(QT, mincolF, lu, lv);   // v-update
  }
  distance_kernel<<<NB * L / 8, 256, 0, stream>>>(Q, minrowF, lu, lv, partial);
  reduce_kernel<<<1, 256, 0, stream>>>(partial, out);
}

// Round 3
// 835.011 us; speedup vs baseline: 2.1011x; 1.3377x over previous
//
#include <hip/hip_runtime.h>
#include <math.h>

#define NB 16
#define L 1024
#define D 256
#define N_ITER 50
#define LOG_MU (-6.9314718055994531f)   // -log(1024) == log_nu
#define QSCALE 2560.0f
#define QS (1.0f/256.0f)                // q*QS = 10*(anchor - C)
#define QSC (1.0f/2560.0f)              // q -> distance units

typedef short short4_t __attribute__((ext_vector_type(4)));

// ---------------- norms: x2[row] = sum_k x[row,k]^2 -----------------
__global__ __launch_bounds__(256) void norms_kernel(
    const float* __restrict__ x, const float* __restrict__ y,
    float* __restrict__ x2, float* __restrict__ y2) {
  int wid = threadIdx.x >> 6, lane = threadIdx.x & 63;
  int row = blockIdx.x * 4 + wid;
  const float* src = (row < NB * L) ? (x + (size_t)row * D)
                                    : (y + (size_t)(row - NB * L) * D);
  float4 v = *(const float4*)(src + lane * 4);
  float s = v.x * v.x + v.y * v.y + v.z * v.z + v.w * v.w;
  #pragma unroll
  for (int off = 32; off; off >>= 1) s += __shfl_down(s, off);
  if (lane == 0) {
    if (row < NB * L) x2[row] = s;
    else              y2[row - NB * L] = s;
  }
}

// ------------- anchor[i] = min over 16 sampled cols of C[i,j] -------------
// Any anchor in [minC_row, minC_row + 12.8) is valid for int16 quantization.
__global__ __launch_bounds__(256) void anchor_kernel(
    const float* __restrict__ x, const float* __restrict__ y,
    const float* __restrict__ x2, const float* __restrict__ y2,
    float* __restrict__ anchor) {
  int w = threadIdx.x >> 6, lane = threadIdx.x & 63;
  int gr = blockIdx.x * 4 + w;           // 0..NB*L-1
  int b = gr >> 10, i = gr & 1023;
  const float* xr = x + (size_t)gr * D;
  float4 xv = *(const float4*)(xr + lane * 4);
  float dots[16];
  #pragma unroll
  for (int s = 0; s < 16; ++s) {
    int j = (i + s * 64 + s * s) & 1023;
    float4 yv = *(const float4*)(y + ((size_t)b * L + j) * D + lane * 4);
    dots[s] = xv.x * yv.x + xv.y * yv.y + xv.z * yv.z + xv.w * yv.w;
  }
  #pragma unroll
  for (int s = 0; s < 16; ++s)
    #pragma unroll
    for (int off = 32; off; off >>= 1) dots[s] += __shfl_xor(dots[s], off);
  if (lane == 0) {
    float xx = x2[gr];
    float mn = 3.4e38f;
    #pragma unroll
    for (int s = 0; s < 16; ++s) {
      int j = (i + s * 64 + s * s) & 1023;
      float d2 = xx + y2[b * L + j] - 2.0f * dots[s];
      mn = fminf(mn, sqrtf(fmaxf(d2, 0.0f)));
    }
    anchor[gr] = mn;
  }
}

// ---------------- single GEMM: quantize Q[i][j] = (anchor_i - C_ij)*2560 ----
__global__ __launch_bounds__(256) void costq_kernel(
    const float* __restrict__ x, const float* __restrict__ y,
    const float* __restrict__ x2, const float* __restrict__ y2,
    const float* __restrict__ anchor, short* __restrict__ Q) {
  __shared__ float xs[16][68];
  __shared__ float ys[16][68];
  int bid = blockIdx.x;
  int b = bid >> 8;
  int rem = bid & 255;
  int i0 = (rem >> 4) << 6;
  int j0 = (rem & 15) << 6;
  int tid = threadIdx.x;
  int tx = tid & 15, ty = tid >> 4;
  int r = tid >> 2, kq = tid & 3;

  float acc[4][4] = {};
  const float* xbase = x + ((size_t)b * L + i0 + r) * D + kq * 4;
  const float* ybase = y + ((size_t)b * L + j0 + r) * D + kq * 4;
  for (int k0 = 0; k0 < D; k0 += 16) {
    float4 xv = *(const float4*)(xbase + k0);
    float4 yv = *(const float4*)(ybase + k0);
    __syncthreads();
    xs[kq * 4 + 0][r] = xv.x; xs[kq * 4 + 1][r] = xv.y;
    xs[kq * 4 + 2][r] = xv.z; xs[kq * 4 + 3][r] = xv.w;
    ys[kq * 4 + 0][r] = yv.x; ys[kq * 4 + 1][r] = yv.y;
    ys[kq * 4 + 2][r] = yv.z; ys[kq * 4 + 3][r] = yv.w;
    __syncthreads();
    #pragma unroll
    for (int kk = 0; kk < 16; ++kk) {
      float4 av = *(const float4*)&xs[kk][ty * 4];
      float4 bv = *(const float4*)&ys[kk][tx * 4];
      float a[4] = {av.x, av.y, av.z, av.w};
      float bb[4] = {bv.x, bv.y, bv.z, bv.w};
      #pragma unroll
      for (int er = 0; er < 4; ++er)
        #pragma unroll
        for (int ec = 0; ec < 4; ++ec)
          acc[er][ec] = fmaf(a[er], bb[ec], acc[er][ec]);
    }
  }
  float xr[4], yc[4], ar[4];
  #pragma unroll
  for (int e = 0; e < 4; ++e) {
    xr[e] = x2[b * L + i0 + ty * 4 + e];
    yc[e] = y2[b * L + j0 + tx * 4 + e];
    ar[e] = anchor[b * L + i0 + ty * 4 + e];
  }
  #pragma unroll
  for (int er = 0; er < 4; ++er) {
    short4_t q4;
    #pragma unroll
    for (int ec = 0; ec < 4; ++ec) {
      float d2 = xr[er] + yc[ec] - 2.0f * acc[er][ec];
      float c = sqrtf(fmaxf(d2, 0.0f));
      int qi = __float2int_rn((ar[er] - c) * QSCALE);
      q4[ec] = (short)min(max(qi, -32767), 32767);
    }
    *(short4_t*)(Q + ((size_t)b * L + i0 + ty * 4 + er) * L + j0 + tx * 4) = q4;
  }
}

// ---- fused pass: row-LSE -> u; accumulate shifted col partials for v ------
// colacc'[j] = sum_i exp(s_ij + u_i + (v_j - m));  terms <= e^few, no shift risk
__global__ __launch_bounds__(256) void pass_fused_kernel(
    const short* __restrict__ Q, const float* __restrict__ anchor,
    const float* __restrict__ vin, float* __restrict__ uout,
    float* __restrict__ partial) {
  __shared__ float4 cacc[4][256];
  int bb = blockIdx.x;                 // 1024 blocks, 16 rows each
  int w = threadIdx.x >> 6, lane = threadIdx.x & 63;
  int b = bb >> 6;
  const float4* g4 = (const float4*)(vin + (b << 10));
  float vv[16];
  float4 a0 = g4[lane * 2], a1 = g4[lane * 2 + 1];
  float4 a2 = g4[128 + lane * 2], a3 = g4[128 + lane * 2 + 1];
  vv[0]=a0.x; vv[1]=a0.y; vv[2]=a0.z; vv[3]=a0.w;
  vv[4]=a1.x; vv[5]=a1.y; vv[6]=a1.z; vv[7]=a1.w;
  vv[8]=a2.x; vv[9]=a2.y; vv[10]=a2.z; vv[11]=a2.w;
  vv[12]=a3.x; vv[13]=a3.y; vv[14]=a3.z; vv[15]=a3.w;
  float m = vv[0];
  #pragma unroll
  for (int t = 1; t < 16; ++t) m = fmaxf(m, vv[t]);
  #pragma unroll
  for (int off = 32; off; off >>= 1) m = fmaxf(m, __shfl_xor(m, off));
  #pragma unroll
  for (int t = 0; t < 16; ++t) vv[t] -= m;
  float E = __expf(LOG_MU - m);
  float colacc[16] = {};

  #define T8(base, V4)                                                   \
    t[base+0] = __expf(fmaf((float)(short)(V4.x), QS, vv[base+0]));      \
    t[base+1] = __expf(fmaf((float)((V4.x) >> 16), QS, vv[base+1]));     \
    t[base+2] = __expf(fmaf((float)(short)(V4.y), QS, vv[base+2]));      \
    t[base+3] = __expf(fmaf((float)((V4.y) >> 16), QS, vv[base+3]));     \
    t[base+4] = __expf(fmaf((float)(short)(V4.z), QS, vv[base+4]));      \
    t[base+5] = __expf(fmaf((float)(V4.z) >> 16), QS, vv[base+5]));      \
    t[base+6] = __expf(fmaf((float)(short)(V4.w), QS, vv[base+6]));      \
    t[base+7] = __expf(fmaf((float)((V4.w) >> 16), QS, vv[base+7]));

  #pragma unroll
  for (int rr = 0; rr < 4; ++rr) {
    int r = bb * 16 + rr * 4 + w;
    const int4* q0 = (const int4*)(Q + (size_t)r * L);
    int4 cA = q0[lane], cB = q0[64 + lane];
    float t[16];
    t[0]  = __expf(fmaf((float)(short)(cA.x), QS, vv[0]));
    t[1]  = __expf(fmaf((float)(cA.x >> 16),  QS, vv[1]));
    t[2]  = __expf(fmaf((float)(short)(cA.y), QS, vv[2]));
    t[3]  = __expf(fmaf((float)(cA.y >> 16),  QS, vv[3]));
    t[4]  = __expf(fmaf((float)(short)(cA.z), QS, vv[4]));
    t[5]  = __expf(fmaf((float)(cA.z >> 16),  QS, vv[5]));
    t[6]  = __expf(fmaf((float)(short)(cA.w), QS, vv[6]));
    t[7]  = __expf(fmaf((float)(cA.w >> 16),  QS, vv[7]));
    t[8]  = __expf(fmaf((float)(short)(cB.x), QS, vv[8]));
    t[9]  = __expf(fmaf((float)(cB.x >> 16),  QS, vv[9]));
    t[10] = __expf(fmaf((float)(short)(cB.y), QS, vv[10]));
    t[11] = __expf(fmaf((float)(cB.y >> 16),  QS, vv[11]));
    t[12] = __expf(fmaf((float)(short)(cB.z), QS, vv[12]));
    t[13] = __expf(fmaf((float)(cB.z >> 16),  QS, vv[13]));
    t[14] = __expf(fmaf((float)(short)(cB.w), QS, vv[14]));
    t[15] = __expf(fmaf((float)(cB.w >> 16),  QS, vv[15]));
    float racc = 0.0f;
    #pragma unroll
    for (int k = 0; k < 16; ++k) racc += t[k];
    #pragma unroll
    for (int off = 32; off; off >>= 1) racc += __shfl_xor(racc, off);
    if (lane == 0)
      uout[r] = LOG_MU + fmaf(10.0f, anchor[r], -m) - __logf(racc);
    float g = E / racc;                     // exp(u_i - 10*anchor_i)
    #pragma unroll
    for (int k = 0; k < 16; ++k) colacc[k] = fmaf(t[k], g, colacc[k]);
  }
  cacc[w][lane * 2]       = {colacc[0], colacc[1], colacc[2], colacc[3]};
  cacc[w][lane * 2 + 1]   = {colacc[4], colacc[5], colacc[6], colacc[7]};
  cacc[w][128 + lane * 2]     = {colacc[8], colacc[9], colacc[10], colacc[11]};
  cacc[w][128 + lane * 2 + 1] = {colacc[12], colacc[13], colacc[14], colacc[15]};
  __syncthreads();
  int tid = threadIdx.x;
  float4 s0 = cacc[0][tid], s1 = cacc[1][tid], s2 = cacc[2][tid], s3 = cacc[3][tid];
  float4 s = {s0.x + s1.x + s2.x + s3.x, s0.y + s1.y + s2.y + s3.y,
              s0.z + s1.z + s2.z + s3.z, s0.w + s1.w + s2.w + s3.w};
  ((float4*)partial)[bb * 256 + tid] = s;
}

// ------- v[j] = LOG_NU - log(sum_p partial) + (vin[j] - m)  (un-shift) ------
__global__ __launch_bounds__(256) void reducev_kernel(
    const float* __restrict__ partial, const float* __restrict__ vin,
    float* __restrict__ vout) {
  __shared__ float red[4];
  int b = blockIdx.x >> 2;
  int tid = threadIdx.x;
  const float* vb = vin + (b << 10);
  float m = fmaxf(fmaxf(vb[tid], vb[tid + 256]), fmaxf(vb[tid + 512], vb[tid + 768]));
  #pragma unroll
  for (int off = 32; off; off >>= 1) m = fmaxf(m, __shfl_xor(m, off));
  int w = tid >> 6;
  if ((tid & 63) == 0) red[w] = m;
  __syncthreads();
  m = fmaxf(fmaxf(red[0], red[1]), fmaxf(red[2], red[3]));
  int j = ((blockIdx.x & 3) << 8) + tid;
  const float* p = partial + (((size_t)b << 6) << 10) + j;
  float s = 0.0f;
  #pragma unroll
  for (int k = 0; k < 64; ++k) s += p[k << 10];
  vout[(b << 10) + j] = LOG_MU - __logf(s) + vb[j] - m;
}

// ---------------- distance partials: sum exp(u+v-10C)*C ----------------
__global__ __launch_bounds__(256) void distance_kernel(
    const short* __restrict__ Q, const float* __restrict__ anchor,
    const float* __restrict__ lu, const float* __restrict__ lv,
    float* __restrict__ pdist) {
  __shared__ float red[4];
  int bb = blockIdx.x;
  int w = threadIdx.x >> 6, lane = threadIdx.x & 63;
  int b = bb >> 6;
  const float4* g4 = (const float4*)(lv + (b << 10));
  float vv[16];
  float4 a0 = g4[lane * 2], a1 = g4[lane * 2 + 1];
  float4 a2 = g4[128 + lane * 2], a3 = g4[128 + lane * 2 + 1];
  vv[0]=a0.x; vv[1]=a0.y; vv[2]=a0.z; vv[3]=a0.w;
  vv[4]=a1.x; vv[5]=a1.y; vv[6]=a1.z; vv[7]=a1.w;
  vv[8]=a2.x; vv[9]=a2.y; vv[10]=a2.z; vv[11]=a2.w;
  vv[12]=a3.x; vv[13]=a3.y; vv[14]=a3.z; vv[15]=a3.w;
  float m = vv[0];
  #pragma unroll
  for (int t = 1; t < 16; ++t) m = fmaxf(m, vv[t]);
  #pragma unroll
  for (int off = 32; off; off >>= 1) m = fmaxf(m, __shfl_xor(m, off));
  #pragma unroll
  for (int t = 0; t < 16; ++t) vv[t] -= m;

  float racc = 0.0f;
  #pragma unroll
  for (int rr = 0; rr < 4; ++rr) {
    int r = bb * 16 + rr * 4 + w;
    float ar = anchor[r];
    float A = fmaf(-10.0f, ar, lu[r]) + m;
    float va[16];
    #pragma unroll
    for (int k = 0; k < 16; ++k) va[k] = vv[k] + A;
    const int4* q0 = (const int4*)(Q + (size_t)r * L);
    int4 cA = q0[lane], cB = q0[64 + lane];
    #define DACC(V, B)                                                      \
      { float qf = (float)(short)(V);                                       \
        float e = __expf(fmaf(qf, QS, va[B]));                              \
        racc = fmaf(e, fmaf(qf, -QSC, ar), racc);                           \
        qf = (float)((V) >> 16);                                            \
        e = __expf(fmaf(qf, QS, va[(B) + 1]));                              \
        racc = fmaf(e, fmaf(qf, -QSC, ar), racc); }
    DACC(cA.x, 0) DACC(cA.y, 2) DACC(cA.z, 4) DACC(cA.w, 6)
    DACC(cB.x, 8) DACC(cB.y, 10) DACC(cB.z, 12) DACC(cB.w, 14)
    #undef DACC
  }
  #pragma unroll
  for (int off = 32; off; off >>= 1) racc += __shfl_xor(racc, off);
  if (lane == 0) red[w] = racc;
  __syncthreads();
  if (threadIdx.x == 0) pdist[bb] = red[0] + red[1] + red[2] + red[3];
}

__global__ __launch_bounds__(256) void finalred_kernel(
    const float* __restrict__ pdist, float* __restrict__ out) {
  __shared__ float red[4];
  int tid = threadIdx.x;
  float s = pdist[tid] + pdist[tid + 256] + pdist[tid + 512] + pdist[tid + 768];
  #pragma unroll
  for (int off = 32; off; off >>= 1) s += __shfl_xor(s, off);
  int w = tid >> 6;
  if ((tid & 63) == 0) red[w] = s;
  __syncthreads();
  if (tid == 0) out[0] = (red[0] + red[1] + red[2] + red[3]) * (1.0f / NB);
}

extern "C" void kernel_launch(void* const* d_in, const int* in_sizes, int n_in,
                              void* d_out, int out_size, void* d_ws, size_t ws_size,
                              hipStream_t stream) {
  const float* x = (const float*)d_in[0];
  const float* y = (const float*)d_in[1];
  float* out = (float*)d_out;
  char* ws = (char*)d_ws;

  const size_t szQ = (size_t)NB * L * L * sizeof(short);        // 32 MB
  const size_t szP = (size_t)NB * 64 * L * sizeof(float);       // 4 MB
  short* Q = (short*)ws;
  float* partial = (float*)(ws + szQ);
  float* x2 = (float*)(ws + szQ + szP);
  float* y2 = x2 + NB * L;
  float* anchor = y2 + NB * L;
  float* lu = anchor + NB * L;
  float* lv = lu + NB * L;
  float* pdist = lv + NB * L;

  hipMemsetAsync(lv, 0, NB * L * sizeof(float), stream);        // v_0 = 0

  norms_kernel<<<2 * NB * L / 4, 256, 0, stream>>>(x, y, x2, y2);
  anchor_kernel<<<NB * L / 4, 256, 0, stream>>>(x, y, x2, y2, anchor);
  costq_kernel<<<NB * 256, 256, 0, stream>>>(x, y, x2, y2, anchor, Q);

  for (int t = 0; t < N_ITER; ++t) {
    pass_fused_kernel<<<NB * L / 16, 256, 0, stream>>>(Q, anchor, lv, lu, partial);
    reducev_kernel<<<NB * L / 256, 256, 0, stream>>>(partial, lv, lv);
  }
  distance_kernel<<<NB * L / 16, 256, 0, stream>>>(Q, anchor, lu, lv, pdist);
  finalred_kernel<<<1, 256, 0, stream>>>(pdist, out);
}